// Round 1
// baseline (323.922 us; speedup 1.0000x reference)
//
#include <hip/hip_runtime.h>
#include <hip/hip_bf16.h>

typedef __attribute__((ext_vector_type(8))) short short8;
typedef __attribute__((ext_vector_type(4))) float f32x4;

#define HSZ 128
#define BM  64
#define NT  512

__device__ __forceinline__ unsigned short f2bf(float f) {
    union { float f; unsigned int u; } c; c.f = f;
    return (unsigned short)((c.u + 0x7FFFu + ((c.u >> 16) & 1u)) >> 16);
}

// Pack W (bf16) as Wp[col][k/8][8] so a B-fragment lane load is 16B contiguous.
// W[k][g*128+i] = ih[g*128+k][i] (k<128) else hh[g*128+(k-128)][i].
__global__ void prep_kernel(const float* __restrict__ ih, const float* __restrict__ hh,
                            const float* __restrict__ ib, const float* __restrict__ hb,
                            unsigned short* __restrict__ Wp, float* __restrict__ bias) {
    int tid = blockIdx.x * blockDim.x + threadIdx.x;   // 0..16383
    int col = tid >> 5;                                // 0..511
    int kg  = tid & 31;                                // 0..31
    int g = col >> 7, i = col & 127;
    short8 pk;
    #pragma unroll
    for (int j = 0; j < 8; ++j) {
        int k = kg * 8 + j;
        float v = (k < HSZ) ? ih[(g * HSZ + k) * HSZ + i]
                            : hh[(g * HSZ + (k - HSZ)) * HSZ + i];
        pk[j] = (short)f2bf(v);
    }
    *reinterpret_cast<short8*>(Wp + col * 256 + kg * 8) = pk;
    if (kg == 0) bias[col] = ib[col] + hb[col];
}

__global__ __launch_bounds__(NT, 2)
void lstm_kernel(const float* __restrict__ x, const float* __restrict__ h0,
                 const float* __restrict__ c0,
                 const unsigned short* __restrict__ Wp,
                 const float* __restrict__ biasp,
                 float* __restrict__ out, long BH) {
    constexpr int PITCH = 264;                 // shorts per LDS row (256 + 8 pad)
    __shared__ unsigned short A_lds[BM * PITCH];   // 33 KB

    const int t = threadIdx.x;
    const long rowBase = (long)blockIdx.x * BM;

    // ---- stage A = [x | h0] (64 rows x 256 k) as bf16 into LDS ----
    {
        const float4* x4 = reinterpret_cast<const float4*>(x + rowBase * HSZ);
        const float4* h4 = reinterpret_cast<const float4*>(h0 + rowBase * HSZ);
        #pragma unroll
        for (int j = 0; j < 4; ++j) {
            int fi = t + j * NT;               // 0..2047
            int row = fi >> 5;
            int c4  = fi & 31;
            float4 vx = x4[fi];
            float4 vh = h4[fi];
            ushort4 px; px.x = f2bf(vx.x); px.y = f2bf(vx.y); px.z = f2bf(vx.z); px.w = f2bf(vx.w);
            ushort4 ph; ph.x = f2bf(vh.x); ph.y = f2bf(vh.y); ph.z = f2bf(vh.z); ph.w = f2bf(vh.w);
            *reinterpret_cast<ushort4*>(&A_lds[row * PITCH + c4 * 4]) = px;
            *reinterpret_cast<ushort4*>(&A_lds[row * PITCH + HSZ + c4 * 4]) = ph;
        }
    }
    __syncthreads();

    const int lane = t & 63;
    const int wid  = t >> 6;
    const int wm = wid & 1;            // row half of block tile
    const int wn = wid >> 1;           // 0..3: intra-gate col quarter
    const int lr = lane & 15;          // A row / B col within fragment
    const int lk = lane >> 4;          // k-group (8 bf16 each)

    const char* Ab = reinterpret_cast<const char*>(A_lds)
                   + (wm * 32 + lr) * (PITCH * 2) + lk * 16;
    const char* Bb = reinterpret_cast<const char*>(Wp)
                   + (wn * 32 + lr) * 512 + lk * 16;

    f32x4 acc[2][2][4] = {};   // [mi][ni][gate]

    #pragma unroll
    for (int ks = 0; ks < 8; ++ks) {
        short8 a0 = *reinterpret_cast<const short8*>(Ab + ks * 64);
        short8 a1 = *reinterpret_cast<const short8*>(Ab + 16 * (PITCH * 2) + ks * 64);
        #pragma unroll
        for (int g = 0; g < 4; ++g) {
            #pragma unroll
            for (int ni = 0; ni < 2; ++ni) {
                short8 b = *reinterpret_cast<const short8*>(
                    Bb + (g * 128 + ni * 16) * 512 + ks * 64);
                acc[0][ni][g] = __builtin_amdgcn_mfma_f32_16x16x32_bf16(a0, b, acc[0][ni][g], 0, 0, 0);
                acc[1][ni][g] = __builtin_amdgcn_mfma_f32_16x16x32_bf16(a1, b, acc[1][ni][g], 0, 0, 0);
            }
        }
    }

    // ---- epilogue: biases + activations, 6 outputs ----
    float bv[2][4];
    #pragma unroll
    for (int ni = 0; ni < 2; ++ni)
        #pragma unroll
        for (int g = 0; g < 4; ++g)
            bv[ni][g] = biasp[g * HSZ + wn * 32 + ni * 16 + lr];

    #pragma unroll
    for (int mi = 0; mi < 2; ++mi) {
        #pragma unroll
        for (int ni = 0; ni < 2; ++ni) {
            #pragma unroll
            for (int r = 0; r < 4; ++r) {
                int row  = wm * 32 + mi * 16 + lk * 4 + r;       // C/D: row=(lane>>4)*4+reg
                int colg = wn * 32 + ni * 16 + lr;               // C/D: col=lane&15
                long pos = (rowBase + row) * HSZ + colg;
                float iv = acc[mi][ni][0][r] + bv[ni][0];
                float fv = acc[mi][ni][1][r] + bv[ni][1];
                float gv = acc[mi][ni][2][r] + bv[ni][2];
                float ov = acc[mi][ni][3][r] + bv[ni][3];
                float c0v = c0[pos];
                float si = 1.f / (1.f + __expf(-iv));
                float sf = 1.f / (1.f + __expf(-fv));
                float tg = 1.f - 2.f / (__expf(2.f * gv) + 1.f);
                float so = 1.f / (1.f + __expf(-ov));
                float c1 = c0v * sf + si * tg;
                float th = 1.f - 2.f / (__expf(2.f * c1) + 1.f);
                out[pos]          = so + th;   // h_1
                out[pos + BH]     = c1;        // c_1
                out[pos + 2 * BH] = iv;        // I
                out[pos + 3 * BH] = fv;        // F
                out[pos + 4 * BH] = gv;        // G
                out[pos + 5 * BH] = ov;        // O
            }
        }
    }
}

extern "C" void kernel_launch(void* const* d_in, const int* in_sizes, int n_in,
                              void* d_out, int out_size, void* d_ws, size_t ws_size,
                              hipStream_t stream) {
    const float* x  = (const float*)d_in[0];
    const float* h0 = (const float*)d_in[1];
    const float* c0 = (const float*)d_in[2];
    const float* ih = (const float*)d_in[3];
    const float* hh = (const float*)d_in[4];
    const float* ib = (const float*)d_in[5];
    const float* hb = (const float*)d_in[6];
    float* out = (float*)d_out;

    unsigned short* Wp = (unsigned short*)d_ws;            // 512*256 bf16 = 256 KB
    float* bias = (float*)((char*)d_ws + 512 * 256 * 2);   // 512 f32

    long BH = in_sizes[2];      // B * H
    long B  = BH / HSZ;

    prep_kernel<<<64, 256, 0, stream>>>(ih, hh, ib, hb, Wp, bias);
    lstm_kernel<<<(int)(B / BM), NT, 0, stream>>>(x, h0, c0, Wp, bias, out, BH);
}

// Round 2
// 297.965 us; speedup vs baseline: 1.0871x; 1.0871x over previous
//
#include <hip/hip_runtime.h>
#include <hip/hip_bf16.h>

typedef __attribute__((ext_vector_type(8))) short short8;
typedef __attribute__((ext_vector_type(4))) float f32x4;

#define HSZ 128
#define BM  64
#define NT  512

__device__ __forceinline__ unsigned short f2bf(float f) {
    union { float f; unsigned int u; } c; c.f = f;
    return (unsigned short)((c.u + 0x7FFFu + ((c.u >> 16) & 1u)) >> 16);
}

// Pack W (bf16) as Wp[col][k] (k contiguous) so a fragment lane load is 16B contiguous.
// W[k][g*128+i] = ih[g*128+k][i] (k<128) else hh[g*128+(k-128)][i].
__global__ void prep_kernel(const float* __restrict__ ih, const float* __restrict__ hh,
                            const float* __restrict__ ib, const float* __restrict__ hb,
                            unsigned short* __restrict__ Wp, float* __restrict__ bias) {
    int tid = blockIdx.x * blockDim.x + threadIdx.x;   // 0..16383
    int col = tid >> 5;                                // 0..511
    int kg  = tid & 31;                                // 0..31
    int g = col >> 7, i = col & 127;
    short8 pk;
    #pragma unroll
    for (int j = 0; j < 8; ++j) {
        int k = kg * 8 + j;
        float v = (k < HSZ) ? ih[(g * HSZ + k) * HSZ + i]
                            : hh[(g * HSZ + (k - HSZ)) * HSZ + i];
        pk[j] = (short)f2bf(v);
    }
    *reinterpret_cast<short8*>(Wp + col * 256 + kg * 8) = pk;
    if (kg == 0) bias[col] = ib[col] + hb[col];
}

__global__ __launch_bounds__(NT, 2)
void lstm_kernel(const float* __restrict__ x, const float* __restrict__ h0,
                 const float* __restrict__ c0,
                 const unsigned short* __restrict__ Wp,
                 const float* __restrict__ biasp,
                 float* __restrict__ out, long BH) {
    constexpr int PITCH = 264;                 // shorts per LDS row (256 + 8 pad)
    __shared__ unsigned short A_lds[BM * PITCH];   // ~33 KB

    const int t = threadIdx.x;
    const long rowBase = (long)blockIdx.x * BM;

    // ---- stage A = [x | h0] (64 rows x 256 k) as bf16 into LDS ----
    {
        const float4* x4 = reinterpret_cast<const float4*>(x + rowBase * HSZ);
        const float4* h4 = reinterpret_cast<const float4*>(h0 + rowBase * HSZ);
        #pragma unroll
        for (int j = 0; j < 4; ++j) {
            int fi = t + j * NT;               // 0..2047
            int row = fi >> 5;
            int c4  = fi & 31;
            float4 vx = x4[fi];
            float4 vh = h4[fi];
            ushort4 px; px.x = f2bf(vx.x); px.y = f2bf(vx.y); px.z = f2bf(vx.z); px.w = f2bf(vx.w);
            ushort4 ph; ph.x = f2bf(vh.x); ph.y = f2bf(vh.y); ph.z = f2bf(vh.z); ph.w = f2bf(vh.w);
            *reinterpret_cast<ushort4*>(&A_lds[row * PITCH + c4 * 4]) = px;
            *reinterpret_cast<ushort4*>(&A_lds[row * PITCH + HSZ + c4 * 4]) = ph;
        }
    }
    __syncthreads();

    const int lane = t & 63;
    const int wid  = t >> 6;
    const int wm = wid & 1;            // row half of block tile (32 rows each)
    const int wn = wid >> 1;           // 0..3: intra-gate col quarter (32 cols)
    const int lr = lane & 15;
    const int lk = lane >> 4;          // k-group (8 bf16 each)

    // Activation fragment (operand B now): col index = batch row = lr
    const char* Ab = reinterpret_cast<const char*>(A_lds)
                   + (wm * 32 + lr) * (PITCH * 2) + lk * 16;
    // W fragment (operand A now): row index = gate col = lr
    const char* Wb = reinterpret_cast<const char*>(Wp)
                   + (wn * 32 + lr) * 512 + lk * 16;

    f32x4 acc[2][2][4] = {};   // [mi (row sub-tile)][ni][gate]

    #pragma unroll
    for (int ks = 0; ks < 8; ++ks) {
        short8 a0 = *reinterpret_cast<const short8*>(Ab + ks * 64);
        short8 a1 = *reinterpret_cast<const short8*>(Ab + 16 * (PITCH * 2) + ks * 64);
        #pragma unroll
        for (int g = 0; g < 4; ++g) {
            #pragma unroll
            for (int ni = 0; ni < 2; ++ni) {
                short8 w = *reinterpret_cast<const short8*>(
                    Wb + (g * 128 + ni * 16) * 512 + ks * 64);
                // Swapped operands: D[gatecol][batchrow]; lane's 4 regs = 4 consecutive gate cols
                acc[0][ni][g] = __builtin_amdgcn_mfma_f32_16x16x32_bf16(w, a0, acc[0][ni][g], 0, 0, 0);
                acc[1][ni][g] = __builtin_amdgcn_mfma_f32_16x16x32_bf16(w, a1, acc[1][ni][g], 0, 0, 0);
            }
        }
    }

    // ---- epilogue: biases + activations, 6 outputs, all float4 ----
    f32x4 bg[2][4];
    #pragma unroll
    for (int ni = 0; ni < 2; ++ni)
        #pragma unroll
        for (int g = 0; g < 4; ++g)
            bg[ni][g] = *reinterpret_cast<const f32x4*>(
                biasp + g * HSZ + wn * 32 + ni * 16 + lk * 4);

    #pragma unroll
    for (int mi = 0; mi < 2; ++mi) {
        const long row = rowBase + wm * 32 + mi * 16 + lr;   // D col = lane&15 = batch row
        #pragma unroll
        for (int ni = 0; ni < 2; ++ni) {
            const long pos = row * HSZ + wn * 32 + ni * 16 + lk * 4;  // D row = lk*4+r = gate col
            f32x4 c0v = *reinterpret_cast<const f32x4*>(c0 + pos);
            f32x4 h1v, c1v, Iv, Fv, Gv, Ov;
            #pragma unroll
            for (int r = 0; r < 4; ++r) {
                float iv = acc[mi][ni][0][r] + bg[ni][0][r];
                float fv = acc[mi][ni][1][r] + bg[ni][1][r];
                float gv = acc[mi][ni][2][r] + bg[ni][2][r];
                float ov = acc[mi][ni][3][r] + bg[ni][3][r];
                float si = 1.f / (1.f + __expf(-iv));
                float sf = 1.f / (1.f + __expf(-fv));
                float tg = 1.f - 2.f / (__expf(2.f * gv) + 1.f);
                float so = 1.f / (1.f + __expf(-ov));
                float c1 = c0v[r] * sf + si * tg;
                float th = 1.f - 2.f / (__expf(2.f * c1) + 1.f);
                h1v[r] = so + th;
                c1v[r] = c1;
                Iv[r] = iv; Fv[r] = fv; Gv[r] = gv; Ov[r] = ov;
            }
            *reinterpret_cast<f32x4*>(out + pos)          = h1v;
            *reinterpret_cast<f32x4*>(out + pos + BH)     = c1v;
            *reinterpret_cast<f32x4*>(out + pos + 2 * BH) = Iv;
            *reinterpret_cast<f32x4*>(out + pos + 3 * BH) = Fv;
            *reinterpret_cast<f32x4*>(out + pos + 4 * BH) = Gv;
            *reinterpret_cast<f32x4*>(out + pos + 5 * BH) = Ov;
        }
    }
}

extern "C" void kernel_launch(void* const* d_in, const int* in_sizes, int n_in,
                              void* d_out, int out_size, void* d_ws, size_t ws_size,
                              hipStream_t stream) {
    const float* x  = (const float*)d_in[0];
    const float* h0 = (const float*)d_in[1];
    const float* c0 = (const float*)d_in[2];
    const float* ih = (const float*)d_in[3];
    const float* hh = (const float*)d_in[4];
    const float* ib = (const float*)d_in[5];
    const float* hb = (const float*)d_in[6];
    float* out = (float*)d_out;

    unsigned short* Wp = (unsigned short*)d_ws;            // 512*256 bf16 = 256 KB
    float* bias = (float*)((char*)d_ws + 512 * 256 * 2);   // 512 f32

    long BH = in_sizes[2];      // B * H
    long B  = BH / HSZ;

    prep_kernel<<<64, 256, 0, stream>>>(ih, hh, ib, hb, Wp, bias);
    lstm_kernel<<<(int)(B / BM), NT, 0, stream>>>(x, h0, c0, Wp, bias, out, BH);
}

// Round 3
// 230.414 us; speedup vs baseline: 1.4058x; 1.2932x over previous
//
#include <hip/hip_runtime.h>
#include <hip/hip_bf16.h>

typedef __attribute__((ext_vector_type(8))) short short8;
typedef __attribute__((ext_vector_type(4))) float f32x4;

#define HSZ 128
#define BM  64
#define NT  512

__device__ __forceinline__ unsigned short f2bf(float f) {
    union { float f; unsigned int u; } c; c.f = f;
    return (unsigned short)((c.u + 0x7FFFu + ((c.u >> 16) & 1u)) >> 16);
}

// Pack W (bf16) as Wp[col][k] (k contiguous, 16B-aligned fragments).
// W[k][g*128+i] = ih[g*128+k][i] (k<128) else hh[g*128+(k-128)][i].
__global__ void prep_kernel(const float* __restrict__ ih, const float* __restrict__ hh,
                            const float* __restrict__ ib, const float* __restrict__ hb,
                            unsigned short* __restrict__ Wp, float* __restrict__ bias) {
    int tid = blockIdx.x * blockDim.x + threadIdx.x;   // 0..16383
    int col = tid >> 5;                                // 0..511
    int kg  = tid & 31;                                // 0..31
    int g = col >> 7, i = col & 127;
    short8 pk;
    #pragma unroll
    for (int j = 0; j < 8; ++j) {
        int k = kg * 8 + j;
        float v = (k < HSZ) ? ih[(g * HSZ + k) * HSZ + i]
                            : hh[(g * HSZ + (k - HSZ)) * HSZ + i];
        pk[j] = (short)f2bf(v);
    }
    *reinterpret_cast<short8*>(Wp + col * 256 + kg * 8) = pk;
    if (kg == 0) bias[col] = ib[col] + hb[col];
}

union SMem {
    unsigned short A[BM * 264];   // 33792 B, bf16 activations (pitch 264 shorts)
    f32x4 O[BM * 32];             // 32768 B, one f32 output tile [64][128]
};

__global__ __launch_bounds__(NT, 2)
void lstm_kernel(const float* __restrict__ x, const float* __restrict__ h0,
                 const float* __restrict__ c0,
                 const unsigned short* __restrict__ Wp,
                 const float* __restrict__ biasp,
                 float* __restrict__ out, long BH) {
    constexpr int PITCH = 264;
    __shared__ SMem sm;

    const int t = threadIdx.x;
    const long rowBase = (long)blockIdx.x * BM;

    // ---- stage A = [x | h0] (64 rows x 256 k) as bf16 into LDS ----
    {
        const float4* x4 = reinterpret_cast<const float4*>(x + rowBase * HSZ);
        const float4* h4 = reinterpret_cast<const float4*>(h0 + rowBase * HSZ);
        #pragma unroll
        for (int j = 0; j < 4; ++j) {
            int fi = t + j * NT;               // 0..2047
            int row = fi >> 5;
            int c4  = fi & 31;
            float4 vx = x4[fi];
            float4 vh = h4[fi];
            ushort4 px; px.x = f2bf(vx.x); px.y = f2bf(vx.y); px.z = f2bf(vx.z); px.w = f2bf(vx.w);
            ushort4 ph; ph.x = f2bf(vh.x); ph.y = f2bf(vh.y); ph.z = f2bf(vh.z); ph.w = f2bf(vh.w);
            *reinterpret_cast<ushort4*>(&sm.A[row * PITCH + c4 * 4]) = px;
            *reinterpret_cast<ushort4*>(&sm.A[row * PITCH + HSZ + c4 * 4]) = ph;
        }
    }
    __syncthreads();

    const int lane = t & 63;
    const int wid  = t >> 6;
    const int wm = wid & 1;            // row half (32 rows)
    const int wn = wid >> 1;           // 0..3: intra-gate col quarter (32 cols)
    const int lr = lane & 15;
    const int lk = lane >> 4;          // k-group (8 bf16)

    // ---- prefetch c0 fragments (consumed after MFMA; latency hidden) ----
    f32x4 c0v[2][2];
    #pragma unroll
    for (int mi = 0; mi < 2; ++mi)
        #pragma unroll
        for (int ni = 0; ni < 2; ++ni) {
            long pos = (rowBase + wm * 32 + mi * 16 + lr) * HSZ
                     + wn * 32 + ni * 16 + lk * 4;
            c0v[mi][ni] = *reinterpret_cast<const f32x4*>(c0 + pos);
        }

    const char* Ab = reinterpret_cast<const char*>(sm.A)
                   + (wm * 32 + lr) * (PITCH * 2) + lk * 16;
    const char* Wb = reinterpret_cast<const char*>(Wp)
                   + (wn * 32 + lr) * 512 + lk * 16;

    f32x4 acc[2][2][4] = {};   // [mi][ni][gate]

    #pragma unroll
    for (int ks = 0; ks < 8; ++ks) {
        short8 a0 = *reinterpret_cast<const short8*>(Ab + ks * 64);
        short8 a1 = *reinterpret_cast<const short8*>(Ab + 16 * (PITCH * 2) + ks * 64);
        #pragma unroll
        for (int g = 0; g < 4; ++g) {
            #pragma unroll
            for (int ni = 0; ni < 2; ++ni) {
                short8 w = *reinterpret_cast<const short8*>(
                    Wb + (g * 128 + ni * 16) * 512 + ks * 64);
                // Swapped operands: lane's 4 acc regs = 4 consecutive gate cols
                acc[0][ni][g] = __builtin_amdgcn_mfma_f32_16x16x32_bf16(w, a0, acc[0][ni][g], 0, 0, 0);
                acc[1][ni][g] = __builtin_amdgcn_mfma_f32_16x16x32_bf16(w, a1, acc[1][ni][g], 0, 0, 0);
            }
        }
    }

    // ---- fold bias into acc (transient registers only) ----
    #pragma unroll
    for (int ni = 0; ni < 2; ++ni)
        #pragma unroll
        for (int g = 0; g < 4; ++g) {
            f32x4 bg = *reinterpret_cast<const f32x4*>(
                biasp + g * HSZ + wn * 32 + ni * 16 + lk * 4);
            acc[0][ni][g] += bg;
            acc[1][ni][g] += bg;
        }

    __syncthreads();   // A tile dead; LDS reused as output tile

    // scatter slots: row-major [64][32 granules], XOR-swizzled
    int sidx[2][2];
    #pragma unroll
    for (int mi = 0; mi < 2; ++mi)
        #pragma unroll
        for (int ni = 0; ni < 2; ++ni) {
            int row = wm * 32 + mi * 16 + lr;
            sidx[mi][ni] = row * 32 + ((wn * 8 + ni * 4 + lk) ^ (row & 7));
        }

    const long base = rowBase * HSZ;
    auto flush = [&](long obase) {
        #pragma unroll
        for (int p = 0; p < 4; ++p) {
            int f = t + p * NT;               // 0..2047 granules
            int row = f >> 5, c = f & 31;
            f32x4 v = sm.O[row * 32 + (c ^ (row & 7))];
            __builtin_nontemporal_store(v,
                reinterpret_cast<f32x4*>(out + obase + (long)f * 4));
        }
    };

    // ---- output 1: c_1 ----
    #pragma unroll
    for (int mi = 0; mi < 2; ++mi)
        #pragma unroll
        for (int ni = 0; ni < 2; ++ni) {
            f32x4 v;
            #pragma unroll
            for (int r = 0; r < 4; ++r) {
                float iv = acc[mi][ni][0][r];
                float fv = acc[mi][ni][1][r];
                float gv = acc[mi][ni][2][r];
                float si = 1.f / (1.f + __expf(-iv));
                float sf = 1.f / (1.f + __expf(-fv));
                float tg = 1.f - 2.f / (__expf(2.f * gv) + 1.f);
                v[r] = c0v[mi][ni][r] * sf + si * tg;
            }
            sm.O[sidx[mi][ni]] = v;
        }
    __syncthreads();
    flush(BH + base);
    __syncthreads();

    // ---- output 0: h_1 = sigmoid(O) + tanh(c_1)  (c_1 read back from own slot) ----
    #pragma unroll
    for (int mi = 0; mi < 2; ++mi)
        #pragma unroll
        for (int ni = 0; ni < 2; ++ni) {
            f32x4 c1 = sm.O[sidx[mi][ni]];
            f32x4 v;
            #pragma unroll
            for (int r = 0; r < 4; ++r) {
                float ov = acc[mi][ni][3][r];
                float so = 1.f / (1.f + __expf(-ov));
                float th = 1.f - 2.f / (__expf(2.f * c1[r]) + 1.f);
                v[r] = so + th;
            }
            sm.O[sidx[mi][ni]] = v;
        }
    __syncthreads();
    flush(base);
    __syncthreads();

    // ---- outputs 2..5: raw gates I, F, G, O ----
    #pragma unroll
    for (int g = 0; g < 4; ++g) {
        #pragma unroll
        for (int mi = 0; mi < 2; ++mi)
            #pragma unroll
            for (int ni = 0; ni < 2; ++ni)
                sm.O[sidx[mi][ni]] = acc[mi][ni][g];
        __syncthreads();
        flush((long)(2 + g) * BH + base);
        if (g < 3) __syncthreads();
    }
}

extern "C" void kernel_launch(void* const* d_in, const int* in_sizes, int n_in,
                              void* d_out, int out_size, void* d_ws, size_t ws_size,
                              hipStream_t stream) {
    const float* x  = (const float*)d_in[0];
    const float* h0 = (const float*)d_in[1];
    const float* c0 = (const float*)d_in[2];
    const float* ih = (const float*)d_in[3];
    const float* hh = (const float*)d_in[4];
    const float* ib = (const float*)d_in[5];
    const float* hb = (const float*)d_in[6];
    float* out = (float*)d_out;

    unsigned short* Wp = (unsigned short*)d_ws;            // 512*256 bf16 = 256 KB
    float* bias = (float*)((char*)d_ws + 512 * 256 * 2);   // 512 f32

    long BH = in_sizes[2];      // B * H
    long B  = BH / HSZ;

    prep_kernel<<<64, 256, 0, stream>>>(ih, hh, ib, hb, Wp, bias);
    lstm_kernel<<<(int)(B / BM), NT, 0, stream>>>(x, h0, c0, Wp, bias, out, BH);
}

// Round 4
// 205.999 us; speedup vs baseline: 1.5724x; 1.1185x over previous
//
#include <hip/hip_runtime.h>
#include <hip/hip_bf16.h>

typedef __attribute__((ext_vector_type(8))) short short8;
typedef __attribute__((ext_vector_type(4))) float f32x4;

#define HSZ 128
#define BM  64
#define NT  512

__device__ __forceinline__ unsigned short f2bf(float f) {
    union { float f; unsigned int u; } c; c.f = f;
    return (unsigned short)((c.u + 0x7FFFu + ((c.u >> 16) & 1u)) >> 16);
}

// Pack W (bf16) as Wp[col][k] (k contiguous, 16B-aligned fragments).
// W[k][g*128+i] = ih[g*128+k][i] (k<128) else hh[g*128+(k-128)][i].
__global__ void prep_kernel(const float* __restrict__ ih, const float* __restrict__ hh,
                            const float* __restrict__ ib, const float* __restrict__ hb,
                            unsigned short* __restrict__ Wp, float* __restrict__ bias) {
    int tid = blockIdx.x * blockDim.x + threadIdx.x;   // 0..16383
    int col = tid >> 5;                                // 0..511
    int kg  = tid & 31;                                // 0..31
    int g = col >> 7, i = col & 127;
    short8 pk;
    #pragma unroll
    for (int j = 0; j < 8; ++j) {
        int k = kg * 8 + j;
        float v = (k < HSZ) ? ih[(g * HSZ + k) * HSZ + i]
                            : hh[(g * HSZ + (k - HSZ)) * HSZ + i];
        pk[j] = (short)f2bf(v);
    }
    *reinterpret_cast<short8*>(Wp + col * 256 + kg * 8) = pk;
    if (kg == 0) bias[col] = ib[col] + hb[col];
}

union SMem {
    unsigned short A[BM * 264];   // 33792 B bf16 activations (dead after MFMA)
    f32x4 T[2][BM * 32];          // 2 x 32 KB f32 output tiles (double buffer)
};

__global__ __launch_bounds__(NT, 4)   // 4 waves/EU -> 2 blocks/CU; caps regs at 128
void lstm_kernel(const float* __restrict__ x, const float* __restrict__ h0,
                 const float* __restrict__ c0,
                 const unsigned short* __restrict__ Wp,
                 const float* __restrict__ biasp,
                 float* __restrict__ out, long BH) {
    constexpr int PITCH = 264;
    __shared__ SMem sm;

    const int t = threadIdx.x;
    const long rowBase = (long)blockIdx.x * BM;

    // ---- stage A = [x | h0] (64 rows x 256 k) as bf16 into LDS ----
    {
        const float4* x4 = reinterpret_cast<const float4*>(x + rowBase * HSZ);
        const float4* h4 = reinterpret_cast<const float4*>(h0 + rowBase * HSZ);
        #pragma unroll
        for (int j = 0; j < 4; ++j) {
            int fi = t + j * NT;               // 0..2047
            int row = fi >> 5;
            int c4  = fi & 31;
            float4 vx = x4[fi];
            float4 vh = h4[fi];
            ushort4 px; px.x = f2bf(vx.x); px.y = f2bf(vx.y); px.z = f2bf(vx.z); px.w = f2bf(vx.w);
            ushort4 ph; ph.x = f2bf(vh.x); ph.y = f2bf(vh.y); ph.z = f2bf(vh.z); ph.w = f2bf(vh.w);
            *reinterpret_cast<ushort4*>(&sm.A[row * PITCH + c4 * 4]) = px;
            *reinterpret_cast<ushort4*>(&sm.A[row * PITCH + HSZ + c4 * 4]) = ph;
        }
    }
    __syncthreads();

    const int lane = t & 63;
    const int wid  = t >> 6;
    const int wm = wid & 1;            // row half (32 rows)
    const int wn = wid >> 1;           // 0..3: intra-gate col quarter (32 cols)
    const int lr = lane & 15;
    const int lk = lane >> 4;          // k-group (8 bf16)

    const char* Ab = reinterpret_cast<const char*>(sm.A)
                   + (wm * 32 + lr) * (PITCH * 2) + lk * 16;
    const char* Wb = reinterpret_cast<const char*>(Wp)
                   + (wn * 32 + lr) * 512 + lk * 16;

    f32x4 acc[2][2][4] = {};   // [mi][ni][gate]

    #pragma unroll
    for (int ks = 0; ks < 8; ++ks) {
        short8 a0 = *reinterpret_cast<const short8*>(Ab + ks * 64);
        short8 a1 = *reinterpret_cast<const short8*>(Ab + 16 * (PITCH * 2) + ks * 64);
        #pragma unroll
        for (int g = 0; g < 4; ++g) {
            #pragma unroll
            for (int ni = 0; ni < 2; ++ni) {
                short8 w = *reinterpret_cast<const short8*>(
                    Wb + (g * 128 + ni * 16) * 512 + ks * 64);
                // Swapped operands: lane's 4 acc regs = 4 consecutive gate cols
                acc[0][ni][g] = __builtin_amdgcn_mfma_f32_16x16x32_bf16(w, a0, acc[0][ni][g], 0, 0, 0);
                acc[1][ni][g] = __builtin_amdgcn_mfma_f32_16x16x32_bf16(w, a1, acc[1][ni][g], 0, 0, 0);
            }
        }
    }

    // ---- c0 load (latency hidden by bias fold + barrier) ----
    f32x4 c0v[2][2];
    #pragma unroll
    for (int mi = 0; mi < 2; ++mi)
        #pragma unroll
        for (int ni = 0; ni < 2; ++ni) {
            long pos = (rowBase + wm * 32 + mi * 16 + lr) * HSZ
                     + wn * 32 + ni * 16 + lk * 4;
            c0v[mi][ni] = *reinterpret_cast<const f32x4*>(c0 + pos);
        }

    // ---- fold bias into acc ----
    #pragma unroll
    for (int ni = 0; ni < 2; ++ni)
        #pragma unroll
        for (int g = 0; g < 4; ++g) {
            f32x4 bg = *reinterpret_cast<const f32x4*>(
                biasp + g * HSZ + wn * 32 + ni * 16 + lk * 4);
            acc[0][ni][g] += bg;
            acc[1][ni][g] += bg;
        }

    __syncthreads();   // A tile dead; LDS reused as output tiles

    const long base = rowBase * HSZ;
    // scatter slot (recomputed inline; row-major [64][32 granules], XOR swizzle)
    #define SIDX(mi, ni) ((wm*32 + (mi)*16 + lr) * 32 + \
                          ((wn*8 + (ni)*4 + lk) ^ ((wm*32 + (mi)*16 + lr) & 7)))

    auto flush = [&](const f32x4* T, long obase) {
        #pragma unroll
        for (int p = 0; p < 4; ++p) {
            int f = t + p * NT;               // 0..2047 granules
            int row = f >> 5, c = f & 31;
            f32x4 v = T[row * 32 + (c ^ (row & 7))];
            __builtin_nontemporal_store(v,
                reinterpret_cast<f32x4*>(out + obase + (long)f * 4));
        }
    };

    // ---- P0: c_1 -> T0 ----
    #pragma unroll
    for (int mi = 0; mi < 2; ++mi)
        #pragma unroll
        for (int ni = 0; ni < 2; ++ni) {
            f32x4 v;
            #pragma unroll
            for (int r = 0; r < 4; ++r) {
                float iv = acc[mi][ni][0][r];
                float fv = acc[mi][ni][1][r];
                float gv = acc[mi][ni][2][r];
                float si = 1.f / (1.f + __expf(-iv));
                float sf = 1.f / (1.f + __expf(-fv));
                float tg = 1.f - 2.f / (__expf(2.f * gv) + 1.f);
                v[r] = c0v[mi][ni][r] * sf + si * tg;
            }
            sm.T[0][SIDX(mi, ni)] = v;
        }
    __syncthreads();

    // ---- P1: flush c_1 || h_1 -> T1 (c_1 read back from T0) ----
    flush(sm.T[0], BH + base);
    #pragma unroll
    for (int mi = 0; mi < 2; ++mi)
        #pragma unroll
        for (int ni = 0; ni < 2; ++ni) {
            f32x4 c1 = sm.T[0][SIDX(mi, ni)];
            f32x4 v;
            #pragma unroll
            for (int r = 0; r < 4; ++r) {
                float ov = acc[mi][ni][3][r];
                float so = 1.f / (1.f + __expf(-ov));
                float th = 1.f - 2.f / (__expf(2.f * c1[r]) + 1.f);
                v[r] = so + th;
            }
            sm.T[1][SIDX(mi, ni)] = v;
        }
    __syncthreads();

    // ---- P2: flush h_1 || I -> T0 ----
    flush(sm.T[1], base);
    #pragma unroll
    for (int mi = 0; mi < 2; ++mi)
        #pragma unroll
        for (int ni = 0; ni < 2; ++ni)
            sm.T[0][SIDX(mi, ni)] = acc[mi][ni][0];
    __syncthreads();

    // ---- P3: flush I || F -> T1 ----
    flush(sm.T[0], 2 * BH + base);
    #pragma unroll
    for (int mi = 0; mi < 2; ++mi)
        #pragma unroll
        for (int ni = 0; ni < 2; ++ni)
            sm.T[1][SIDX(mi, ni)] = acc[mi][ni][1];
    __syncthreads();

    // ---- P4: flush F || G -> T0 ----
    flush(sm.T[1], 3 * BH + base);
    #pragma unroll
    for (int mi = 0; mi < 2; ++mi)
        #pragma unroll
        for (int ni = 0; ni < 2; ++ni)
            sm.T[0][SIDX(mi, ni)] = acc[mi][ni][2];
    __syncthreads();

    // ---- P5: flush G || O -> T1 ----
    flush(sm.T[0], 4 * BH + base);
    #pragma unroll
    for (int mi = 0; mi < 2; ++mi)
        #pragma unroll
        for (int ni = 0; ni < 2; ++ni)
            sm.T[1][SIDX(mi, ni)] = acc[mi][ni][3];
    __syncthreads();

    // ---- P6: flush O ----
    flush(sm.T[1], 5 * BH + base);
    #undef SIDX
}

extern "C" void kernel_launch(void* const* d_in, const int* in_sizes, int n_in,
                              void* d_out, int out_size, void* d_ws, size_t ws_size,
                              hipStream_t stream) {
    const float* x  = (const float*)d_in[0];
    const float* h0 = (const float*)d_in[1];
    const float* c0 = (const float*)d_in[2];
    const float* ih = (const float*)d_in[3];
    const float* hh = (const float*)d_in[4];
    const float* ib = (const float*)d_in[5];
    const float* hb = (const float*)d_in[6];
    float* out = (float*)d_out;

    unsigned short* Wp = (unsigned short*)d_ws;            // 512*256 bf16 = 256 KB
    float* bias = (float*)((char*)d_ws + 512 * 256 * 2);   // 512 f32

    long BH = in_sizes[2];      // B * H
    long B  = BH / HSZ;

    prep_kernel<<<64, 256, 0, stream>>>(ih, hh, ib, hb, Wp, bias);
    lstm_kernel<<<(int)(B / BM), NT, 0, stream>>>(x, h0, c0, Wp, bias, out, BH);
}